// Round 1
// baseline (1407.694 us; speedup 1.0000x reference)
//
#include <hip/hip_runtime.h>

// Problem constants (fixed by the reference setup)
#define N_NODES 50000
#define IN_DIM 256
#define OUT_DIM 128
#define NNZ 800000   // both feature and adjacency nnz

// -----------------------------------------------------------------------------
// Phase 1: xw1[r,:] += v * W1[c,:], xw2[r,:] += v * W2[c,:]
// One (edge, column) pair per thread: 128 threads cover an edge's 128 cols.
// -----------------------------------------------------------------------------
__global__ void feat_spmm_kernel(const int* __restrict__ row,
                                 const int* __restrict__ col,
                                 const float* __restrict__ vals,
                                 const float* __restrict__ W1,
                                 const float* __restrict__ W2,
                                 float* __restrict__ xw1,
                                 float* __restrict__ xw2) {
    int tid = blockIdx.x * blockDim.x + threadIdx.x;   // < NNZ*128 < 2^31
    int e = tid >> 7;          // edge index
    int d = tid & 127;         // output column
    if (e >= NNZ) return;
    int r = row[e];
    int c = col[e];
    float v = vals[e];
    atomicAdd(&xw1[r * OUT_DIM + d], v * W1[c * OUT_DIM + d]);
    atomicAdd(&xw2[r * OUT_DIM + d], v * W2[c * OUT_DIM + d]);
}

// -----------------------------------------------------------------------------
// Phase 2: out[r,:] += v1 * xw1[c,:]  (adj1)  and  out[r,:] += v2 * xw2[c,:]
// Both relations accumulate into the same output buffer (sum precedes ReLU).
// -----------------------------------------------------------------------------
__global__ void adj_spmm_kernel(const int* __restrict__ row1,
                                const int* __restrict__ col1,
                                const float* __restrict__ vals1,
                                const int* __restrict__ row2,
                                const int* __restrict__ col2,
                                const float* __restrict__ vals2,
                                const float* __restrict__ xw1,
                                const float* __restrict__ xw2,
                                float* __restrict__ out) {
    int tid = blockIdx.x * blockDim.x + threadIdx.x;
    int e = tid >> 7;
    int d = tid & 127;
    if (e >= NNZ) return;

    int r1 = row1[e];
    int c1 = col1[e];
    float v1 = vals1[e];
    atomicAdd(&out[r1 * OUT_DIM + d], v1 * xw1[c1 * OUT_DIM + d]);

    int r2 = row2[e];
    int c2 = col2[e];
    float v2 = vals2[e];
    atomicAdd(&out[r2 * OUT_DIM + d], v2 * xw2[c2 * OUT_DIM + d]);
}

// -----------------------------------------------------------------------------
// Phase 3: in-place ReLU
// -----------------------------------------------------------------------------
__global__ void relu_kernel(float* __restrict__ out, int n) {
    int i = blockIdx.x * blockDim.x + threadIdx.x;
    if (i < n) out[i] = fmaxf(out[i], 0.0f);
}

extern "C" void kernel_launch(void* const* d_in, const int* in_sizes, int n_in,
                              void* d_out, int out_size, void* d_ws, size_t ws_size,
                              hipStream_t stream) {
    const int*   feat_row  = (const int*)  d_in[0];
    const int*   feat_col  = (const int*)  d_in[1];
    const float* feat_vals = (const float*)d_in[2];
    const int*   adj1_row  = (const int*)  d_in[3];
    const int*   adj1_col  = (const int*)  d_in[4];
    const float* adj1_vals = (const float*)d_in[5];
    const int*   adj2_row  = (const int*)  d_in[6];
    const int*   adj2_col  = (const int*)  d_in[7];
    const float* adj2_vals = (const float*)d_in[8];
    const float* W1        = (const float*)d_in[9];
    const float* W2        = (const float*)d_in[10];
    // d_in[11] = n_nodes (compile-time constant here)

    float* out = (float*)d_out;
    float* xw1 = (float*)d_ws;                         // [N_NODES, OUT_DIM]
    float* xw2 = xw1 + (size_t)N_NODES * OUT_DIM;      // [N_NODES, OUT_DIM]

    const size_t xw_bytes  = (size_t)N_NODES * OUT_DIM * sizeof(float);
    const size_t out_bytes = (size_t)N_NODES * OUT_DIM * sizeof(float);

    // Workspace and output are re-poisoned to 0xAA before every launch — zero them.
    hipMemsetAsync(d_ws, 0, 2 * xw_bytes, stream);
    hipMemsetAsync(d_out, 0, out_bytes, stream);

    const int block = 256;
    const int threads_per_phase = NNZ * OUT_DIM;       // 102.4M
    const int grid_edges = (threads_per_phase + block - 1) / block;   // 400000

    feat_spmm_kernel<<<grid_edges, block, 0, stream>>>(
        feat_row, feat_col, feat_vals, W1, W2, xw1, xw2);

    adj_spmm_kernel<<<grid_edges, block, 0, stream>>>(
        adj1_row, adj1_col, adj1_vals,
        adj2_row, adj2_col, adj2_vals,
        xw1, xw2, out);

    const int n_out = N_NODES * OUT_DIM;
    relu_kernel<<<(n_out + block - 1) / block, block, 0, stream>>>(out, n_out);
}

// Round 2
// 486.954 us; speedup vs baseline: 2.8908x; 2.8908x over previous
//
#include <hip/hip_runtime.h>

// Problem constants (fixed by the reference setup)
#define N_NODES 50000
#define IN_DIM 256
#define OUT_DIM 128
#define NNZ 800000          // nnz for feat, adj1, adj2 each
#define SCAN_N (3 * N_NODES)        // 150000 row counters (feat | adj1 | adj2)
#define TOTAL_NNZ (3 * NNZ)         // 2.4M sorted entries
#define SCAN_BLOCKS ((SCAN_N + 255) / 256)   // 586

// -----------------------------------------------------------------------------
// CSR build: histogram -> exclusive scan -> scatter (counting sort by row).
// Segment layout in the unified arrays: feat rows [0,50000), adj1 [50000,100000),
// adj2 [100000,150000). Sorted entries: feat [0,800K), adj1 [800K,1.6M),
// adj2 [1.6M,2.4M) — the continuous scan produces exactly this.
// -----------------------------------------------------------------------------
__global__ void hist_kernel(const int* __restrict__ fr,
                            const int* __restrict__ a1r,
                            const int* __restrict__ a2r,
                            int* __restrict__ cnt) {
    int e = blockIdx.x * blockDim.x + threadIdx.x;
    if (e >= NNZ) return;
    atomicAdd(&cnt[fr[e]], 1);
    atomicAdd(&cnt[N_NODES + a1r[e]], 1);
    atomicAdd(&cnt[2 * N_NODES + a2r[e]], 1);
}

__global__ void scan_block_kernel(const int* __restrict__ cnt,
                                  int* __restrict__ starts,
                                  int* __restrict__ bsum) {
    __shared__ int tmp[256];
    int g = blockIdx.x * 256 + threadIdx.x;
    int v = (g < SCAN_N) ? cnt[g] : 0;
    tmp[threadIdx.x] = v;
    __syncthreads();
    for (int off = 1; off < 256; off <<= 1) {
        int t = (threadIdx.x >= off) ? tmp[threadIdx.x - off] : 0;
        __syncthreads();
        tmp[threadIdx.x] += t;
        __syncthreads();
    }
    int incl = tmp[threadIdx.x];
    if (g < SCAN_N) starts[g] = incl - v;          // exclusive
    if (threadIdx.x == 255) bsum[blockIdx.x] = incl;
}

__global__ void scan_bsum_kernel(int* __restrict__ bsum, int nb) {
    __shared__ int tmp[1024];
    int t = threadIdx.x;
    int v = (t < nb) ? bsum[t] : 0;
    tmp[t] = v;
    __syncthreads();
    for (int off = 1; off < 1024; off <<= 1) {
        int x = (t >= off) ? tmp[t - off] : 0;
        __syncthreads();
        tmp[t] += x;
        __syncthreads();
    }
    if (t < nb) bsum[t] = tmp[t] - v;              // exclusive block offsets
}

__global__ void scan_add_kernel(int* __restrict__ starts,
                                const int* __restrict__ bsum,
                                int* __restrict__ cursor) {
    int g = blockIdx.x * 256 + threadIdx.x;
    if (g < SCAN_N) {
        int s = starts[g] + bsum[blockIdx.x];
        starts[g] = s;
        cursor[g] = s;
    }
}

__global__ void scatter_kernel(const int* __restrict__ fr, const int* __restrict__ fc,
                               const float* __restrict__ fv,
                               const int* __restrict__ a1r, const int* __restrict__ a1c,
                               const float* __restrict__ a1v,
                               const int* __restrict__ a2r, const int* __restrict__ a2c,
                               const float* __restrict__ a2v,
                               int* __restrict__ cursor,
                               int* __restrict__ scol, float* __restrict__ sval) {
    int e = blockIdx.x * blockDim.x + threadIdx.x;
    if (e >= NNZ) return;
    int p;
    p = atomicAdd(&cursor[fr[e]], 1);
    scol[p] = fc[e];  sval[p] = fv[e];
    p = atomicAdd(&cursor[N_NODES + a1r[e]], 1);
    scol[p] = a1c[e]; sval[p] = a1v[e];
    p = atomicAdd(&cursor[2 * N_NODES + a2r[e]], 1);
    scol[p] = a2c[e]; sval[p] = a2v[e];
}

// -----------------------------------------------------------------------------
// Phase 1: per-row gather  xw{1,2}[r,:] = sum_e v_e * W{1,2}[c_e,:]
// 32 lanes per row, float4 per lane (128 cols). No atomics, single write.
// -----------------------------------------------------------------------------
__global__ void feat_gather_kernel(const int* __restrict__ starts,
                                   const int* __restrict__ scol,
                                   const float* __restrict__ sval,
                                   const float4* __restrict__ W1,
                                   const float4* __restrict__ W2,
                                   float4* __restrict__ xw1,
                                   float4* __restrict__ xw2) {
    int lane = threadIdx.x & 31;
    int sub  = threadIdx.x >> 5;
    int r = blockIdx.x * 8 + sub;
    if (r >= N_NODES) return;
    int s = starts[r];
    int e = starts[r + 1];            // starts[50000] == 800000 (adj1 base) — correct end
    float4 a1 = make_float4(0.f, 0.f, 0.f, 0.f);
    float4 a2 = make_float4(0.f, 0.f, 0.f, 0.f);
    for (int i = s; i < e; i++) {
        int c = scol[i];
        float v = sval[i];
        float4 w1 = W1[c * 32 + lane];
        float4 w2 = W2[c * 32 + lane];
        a1.x += v * w1.x; a1.y += v * w1.y; a1.z += v * w1.z; a1.w += v * w1.w;
        a2.x += v * w2.x; a2.y += v * w2.y; a2.z += v * w2.z; a2.w += v * w2.w;
    }
    xw1[r * 32 + lane] = a1;
    xw2[r * 32 + lane] = a2;
}

// -----------------------------------------------------------------------------
// Phase 2: out[r,:] = relu( sum_adj1 v*xw1[c,:] + sum_adj2 v*xw2[c,:] )
// -----------------------------------------------------------------------------
__global__ void adj_gather_kernel(const int* __restrict__ starts,
                                  const int* __restrict__ scol,
                                  const float* __restrict__ sval,
                                  const float4* __restrict__ xw1,
                                  const float4* __restrict__ xw2,
                                  float4* __restrict__ out) {
    int lane = threadIdx.x & 31;
    int sub  = threadIdx.x >> 5;
    int r = blockIdx.x * 8 + sub;
    if (r >= N_NODES) return;
    int s1 = starts[N_NODES + r];
    int e1 = starts[N_NODES + r + 1];        // starts[100000] == 1.6M (adj2 base) — correct
    int s2 = starts[2 * N_NODES + r];
    int e2 = (r == N_NODES - 1) ? TOTAL_NNZ : starts[2 * N_NODES + r + 1];
    float4 acc = make_float4(0.f, 0.f, 0.f, 0.f);
    for (int i = s1; i < e1; i++) {
        int c = scol[i];
        float v = sval[i];
        float4 x = xw1[c * 32 + lane];
        acc.x += v * x.x; acc.y += v * x.y; acc.z += v * x.z; acc.w += v * x.w;
    }
    for (int i = s2; i < e2; i++) {
        int c = scol[i];
        float v = sval[i];
        float4 x = xw2[c * 32 + lane];
        acc.x += v * x.x; acc.y += v * x.y; acc.z += v * x.z; acc.w += v * x.w;
    }
    acc.x = fmaxf(acc.x, 0.f); acc.y = fmaxf(acc.y, 0.f);
    acc.z = fmaxf(acc.z, 0.f); acc.w = fmaxf(acc.w, 0.f);
    out[r * 32 + lane] = acc;
}

extern "C" void kernel_launch(void* const* d_in, const int* in_sizes, int n_in,
                              void* d_out, int out_size, void* d_ws, size_t ws_size,
                              hipStream_t stream) {
    const int*   feat_row  = (const int*)  d_in[0];
    const int*   feat_col  = (const int*)  d_in[1];
    const float* feat_vals = (const float*)d_in[2];
    const int*   adj1_row  = (const int*)  d_in[3];
    const int*   adj1_col  = (const int*)  d_in[4];
    const float* adj1_vals = (const float*)d_in[5];
    const int*   adj2_row  = (const int*)  d_in[6];
    const int*   adj2_col  = (const int*)  d_in[7];
    const float* adj2_vals = (const float*)d_in[8];
    const float* W1        = (const float*)d_in[9];
    const float* W2        = (const float*)d_in[10];

    // Workspace layout (all 16B-aligned offsets)
    char* ws = (char*)d_ws;
    float* xw1   = (float*)ws;                                   ws += (size_t)N_NODES * OUT_DIM * 4;  // 25.6 MB
    float* xw2   = (float*)ws;                                   ws += (size_t)N_NODES * OUT_DIM * 4;  // 25.6 MB
    int*   scol  = (int*)ws;                                     ws += (size_t)TOTAL_NNZ * 4;          // 9.6 MB
    float* sval  = (float*)ws;                                   ws += (size_t)TOTAL_NNZ * 4;          // 9.6 MB
    int*   cnt   = (int*)ws;                                     ws += (size_t)SCAN_N * 4;             // 600 KB
    int*   starts= (int*)ws;                                     ws += (size_t)SCAN_N * 4;             // 600 KB
    int*   cursor= (int*)ws;                                     ws += (size_t)SCAN_N * 4;             // 600 KB
    int*   bsum  = (int*)ws;                                     ws += 1024 * 4;

    // Zero only the histogram counters (everything else is fully overwritten).
    hipMemsetAsync(cnt, 0, SCAN_N * sizeof(int), stream);

    const int block = 256;
    const int grid_e = (NNZ + block - 1) / block;                // 3125

    hist_kernel<<<grid_e, block, 0, stream>>>(feat_row, adj1_row, adj2_row, cnt);
    scan_block_kernel<<<SCAN_BLOCKS, 256, 0, stream>>>(cnt, starts, bsum);
    scan_bsum_kernel<<<1, 1024, 0, stream>>>(bsum, SCAN_BLOCKS);
    scan_add_kernel<<<SCAN_BLOCKS, 256, 0, stream>>>(starts, bsum, cursor);
    scatter_kernel<<<grid_e, block, 0, stream>>>(
        feat_row, feat_col, feat_vals,
        adj1_row, adj1_col, adj1_vals,
        adj2_row, adj2_col, adj2_vals,
        cursor, scol, sval);

    const int grid_rows = (N_NODES + 7) / 8;                     // 6250 blocks, 8 rows each
    feat_gather_kernel<<<grid_rows, 256, 0, stream>>>(
        starts, scol, sval, (const float4*)W1, (const float4*)W2,
        (float4*)xw1, (float4*)xw2);
    adj_gather_kernel<<<grid_rows, 256, 0, stream>>>(
        starts, scol, sval, (const float4*)xw1, (const float4*)xw2,
        (float4*)d_out);
}